// Round 8
// baseline (60.896 us; speedup 1.0000x reference)
//
#include <hip/hip_runtime.h>
#include <stdint.h>

#define DIMS 96
#define VEC 4
#define LANES (DIMS / VEC)        // 24 lanes cover one 96-dim row as float4
#define SEGS_PER_BLOCK 8
#define THREADS (LANES * SEGS_PER_BLOCK)  // 192 threads = 3 waves
#define UNROLL 8

// clang native vector type: __builtin_nontemporal_* requires a real vector
// type, not HIP's struct-based float4.
typedef float vfloat4 __attribute__((ext_vector_type(4)));

// Round-8: round-6 structure + nontemporal streaming accesses (round-7 retry;
// compile fix: ext_vector_type instead of HIP float4 for nt builtins).
// Theory: pinned at ~3.7 TB/s L2-miss traffic; output/idx/self streams evict
// emb table lines from the 4 MiB/XCD L2 (FETCH 149 MB vs ~84 MB compulsory).
// nt = evict-first in TCC -> reserve L2 for the gather table.
// NOTE: harness delivers integer inputs as int32.

__global__ __launch_bounds__(256) void bounds_kernel(
    const int* __restrict__ seg, int* __restrict__ bounds, int B, int E)
{
    const int t = blockIdx.x * blockDim.x + threadIdx.x;
    if (t > B) return;
    int lo = 0, hi = E;
    while (lo < hi) {
        const int mid = (lo + hi) >> 1;
        if (seg[mid] < t) lo = mid + 1; else hi = mid;
    }
    bounds[t] = lo;
}

__global__ __launch_bounds__(THREADS) void seg_mean_concat_kernel(
    const float* __restrict__ emb,        // [N, 96]
    const float* __restrict__ self_feats, // [B, 96]
    const int*   __restrict__ nidx,       // [E] int32
    const int*   __restrict__ seg,        // [E] int32, sorted
    const int*   __restrict__ bounds,     // [B+1] or nullptr
    float* __restrict__ out,              // [B, 192]
    int B, int E)
{
    const int tid  = threadIdx.x;
    const int g    = tid / LANES;
    const int lane = tid - g * LANES;
    const int b    = blockIdx.x * SEGS_PER_BLOCK + g;
    if (b >= B) return;

    int start, end;
    if (bounds) {
        start = __builtin_nontemporal_load(bounds + b);
        end   = __builtin_nontemporal_load(bounds + b + 1);
    } else {
        // fallback (ws too small): per-thread in-register search, barrier-free
        int lo = 0, hi = E;
        while (lo < hi) { int m = (lo + hi) >> 1; if (seg[m] < b) lo = m + 1; else hi = m; }
        start = lo;
        hi = E;
        while (lo < hi) { int m = (lo + hi) >> 1; if (seg[m] < b + 1) lo = m + 1; else hi = m; }
        end = lo;
    }

    const vfloat4* __restrict__ embv = (const vfloat4*)emb;

    // streamed once; keep out of L2 (nt)
    const vfloat4* sfp = (const vfloat4*)(self_feats + (size_t)b * DIMS + lane * VEC);
    const vfloat4 sf = __builtin_nontemporal_load(sfp);

    vfloat4 a0 = (vfloat4)(0.f);
    vfloat4 a1 = (vfloat4)(0.f);

    const int last = end - 1;
    if (start <= last) {
        int j[UNROLL];
        // prologue: first 8 clamped indices (nt: idx array is streamed once)
#pragma unroll
        for (int k = 0; k < UNROLL; ++k) {
            int ee = start + k;
            ee = ee > last ? last : ee;
            j[k] = __builtin_nontemporal_load(nidx + ee);
        }
        __builtin_amdgcn_sched_group_barrier(0x20 /*VMEM_READ*/, UNROLL, 0);

        for (int e = start; e <= last; e += UNROLL) {
            // issue 8 independent row gathers (cached: emb owns the L2)
            vfloat4 v[UNROLL];
#pragma unroll
            for (int k = 0; k < UNROLL; ++k)
                v[k] = embv[(size_t)j[k] * LANES + lane];
            __builtin_amdgcn_sched_group_barrier(0x20 /*VMEM_READ*/, UNROLL, 0);

            // prefetch next iteration's indices (stay in flight through accum)
            const int en = e + UNROLL;
            if (en <= last) {
#pragma unroll
                for (int k = 0; k < UNROLL; ++k) {
                    int ee = en + k;
                    ee = ee > last ? last : ee;
                    j[k] = __builtin_nontemporal_load(nidx + ee);
                }
                __builtin_amdgcn_sched_group_barrier(0x20 /*VMEM_READ*/, UNROLL, 0);
            }

            // masked accumulate (dual accumulators for VALU ILP)
#pragma unroll
            for (int k = 0; k < UNROLL; k += 2) {
                const float w0 = (e + k     <= last) ? 1.0f : 0.0f;
                const float w1 = (e + k + 1 <= last) ? 1.0f : 0.0f;
                a0 += v[k] * w0;
                a1 += v[k + 1] * w1;
            }
        }
    }

    const int cnt = end - start;
    const float inv = 1.0f / (float)(cnt > 0 ? cnt : 1);
    const vfloat4 mean = (a0 + a1) * inv;
    const vfloat4 diff = sf - mean;

    // output is a pure stream: nt store keeps it out of L2
    float* orow = out + (size_t)b * (2 * DIMS);
    __builtin_nontemporal_store(mean, (vfloat4*)(orow + lane * VEC));
    __builtin_nontemporal_store(diff, (vfloat4*)(orow + DIMS + lane * VEC));
}

extern "C" void kernel_launch(void* const* d_in, const int* in_sizes, int n_in,
                              void* d_out, int out_size, void* d_ws, size_t ws_size,
                              hipStream_t stream) {
    const float* emb        = (const float*)d_in[0];
    const float* self_feats = (const float*)d_in[1];
    const int*   nidx       = (const int*)d_in[2];
    const int*   seg        = (const int*)d_in[3];
    float*       out        = (float*)d_out;

    const int B = in_sizes[1] / DIMS;   // self_feats is [B, 96]
    const int E = in_sizes[2];          // neighbor_idx length

    int* bounds = nullptr;
    if (ws_size >= (size_t)(B + 1) * sizeof(int)) {
        bounds = (int*)d_ws;
        const int bgrid = (B + 1 + 255) / 256;
        hipLaunchKernelGGL(bounds_kernel, dim3(bgrid), dim3(256), 0, stream,
                           seg, bounds, B, E);
    }

    const int grid = (B + SEGS_PER_BLOCK - 1) / SEGS_PER_BLOCK;
    hipLaunchKernelGGL(seg_mean_concat_kernel, dim3(grid), dim3(THREADS), 0, stream,
                       emb, self_feats, nidx, seg, bounds, out, B, E);
}

// Round 9
// 58.490 us; speedup vs baseline: 1.0411x; 1.0411x over previous
//
#include <hip/hip_runtime.h>
#include <stdint.h>

#define DIMS 96
#define VEC 4
#define LANES (DIMS / VEC)        // 24 lanes cover one 96-dim row as float4
#define SEGS_PER_BLOCK 8
#define THREADS (LANES * SEGS_PER_BLOCK)  // 192 threads = 3 waves
#define UNROLL 8

// clang native vector type: __builtin_nontemporal_* requires a real vector
// type, not HIP's struct-based float4.
typedef float vfloat4 __attribute__((ext_vector_type(4)));

// Round-9: main kernel identical to round 8 (at its random-gather concurrency
// ceiling: ILP-deepening, +occupancy, and nt-stream control all null).
// Change: bounds via one streaming transition-scan pass over sorted seg
// (thread e writes bounds[t]=e+1 for seg[e] < t <= seg[e+1]) instead of 50k
// 20-step dependent binary searches (~8us critical path -> ~1.5us).
// NOTE: harness delivers integer inputs as int32.

__global__ __launch_bounds__(256) void bounds_scan_kernel(
    const int* __restrict__ seg, int* __restrict__ bounds, int B, int E)
{
    const int e = blockIdx.x * blockDim.x + threadIdx.x;
    if (e >= E) return;
    const int s1 = seg[e];
    if (e == 0) {
        // lower_bound(t)=0 for all t <= seg[0]
        for (int t = 0; t <= s1; ++t) bounds[t] = 0;
    }
    if (e + 1 < E) {
        const int s2 = seg[e + 1];
        // lower_bound(t)=e+1 for seg[e] < t <= seg[e+1]
        for (int t = s1 + 1; t <= s2; ++t) bounds[t] = e + 1;
    } else {
        // tail: lower_bound(t)=E for all t > seg[E-1] (includes bounds[B])
        for (int t = s1 + 1; t <= B; ++t) bounds[t] = E;
    }
}

__global__ __launch_bounds__(THREADS) void seg_mean_concat_kernel(
    const float* __restrict__ emb,        // [N, 96]
    const float* __restrict__ self_feats, // [B, 96]
    const int*   __restrict__ nidx,       // [E] int32
    const int*   __restrict__ seg,        // [E] int32, sorted
    const int*   __restrict__ bounds,     // [B+1] or nullptr
    float* __restrict__ out,              // [B, 192]
    int B, int E)
{
    const int tid  = threadIdx.x;
    const int g    = tid / LANES;
    const int lane = tid - g * LANES;
    const int b    = blockIdx.x * SEGS_PER_BLOCK + g;
    if (b >= B) return;

    int start, end;
    if (bounds) {
        start = __builtin_nontemporal_load(bounds + b);
        end   = __builtin_nontemporal_load(bounds + b + 1);
    } else {
        // fallback (ws too small): per-thread in-register search, barrier-free
        int lo = 0, hi = E;
        while (lo < hi) { int m = (lo + hi) >> 1; if (seg[m] < b) lo = m + 1; else hi = m; }
        start = lo;
        hi = E;
        while (lo < hi) { int m = (lo + hi) >> 1; if (seg[m] < b + 1) lo = m + 1; else hi = m; }
        end = lo;
    }

    const vfloat4* __restrict__ embv = (const vfloat4*)emb;

    // streamed once; keep out of L2 (nt)
    const vfloat4* sfp = (const vfloat4*)(self_feats + (size_t)b * DIMS + lane * VEC);
    const vfloat4 sf = __builtin_nontemporal_load(sfp);

    vfloat4 a0 = (vfloat4)(0.f);
    vfloat4 a1 = (vfloat4)(0.f);

    const int last = end - 1;
    if (start <= last) {
        int j[UNROLL];
        // prologue: first 8 clamped indices (nt: idx array is streamed once)
#pragma unroll
        for (int k = 0; k < UNROLL; ++k) {
            int ee = start + k;
            ee = ee > last ? last : ee;
            j[k] = __builtin_nontemporal_load(nidx + ee);
        }
        __builtin_amdgcn_sched_group_barrier(0x20 /*VMEM_READ*/, UNROLL, 0);

        for (int e = start; e <= last; e += UNROLL) {
            // issue 8 independent row gathers (cached: emb owns the L2)
            vfloat4 v[UNROLL];
#pragma unroll
            for (int k = 0; k < UNROLL; ++k)
                v[k] = embv[(size_t)j[k] * LANES + lane];
            __builtin_amdgcn_sched_group_barrier(0x20 /*VMEM_READ*/, UNROLL, 0);

            // prefetch next iteration's indices (stay in flight through accum)
            const int en = e + UNROLL;
            if (en <= last) {
#pragma unroll
                for (int k = 0; k < UNROLL; ++k) {
                    int ee = en + k;
                    ee = ee > last ? last : ee;
                    j[k] = __builtin_nontemporal_load(nidx + ee);
                }
                __builtin_amdgcn_sched_group_barrier(0x20 /*VMEM_READ*/, UNROLL, 0);
            }

            // masked accumulate (dual accumulators for VALU ILP)
#pragma unroll
            for (int k = 0; k < UNROLL; k += 2) {
                const float w0 = (e + k     <= last) ? 1.0f : 0.0f;
                const float w1 = (e + k + 1 <= last) ? 1.0f : 0.0f;
                a0 += v[k] * w0;
                a1 += v[k + 1] * w1;
            }
        }
    }

    const int cnt = end - start;
    const float inv = 1.0f / (float)(cnt > 0 ? cnt : 1);
    const vfloat4 mean = (a0 + a1) * inv;
    const vfloat4 diff = sf - mean;

    // output is a pure stream: nt store keeps it out of L2
    float* orow = out + (size_t)b * (2 * DIMS);
    __builtin_nontemporal_store(mean, (vfloat4*)(orow + lane * VEC));
    __builtin_nontemporal_store(diff, (vfloat4*)(orow + DIMS + lane * VEC));
}

extern "C" void kernel_launch(void* const* d_in, const int* in_sizes, int n_in,
                              void* d_out, int out_size, void* d_ws, size_t ws_size,
                              hipStream_t stream) {
    const float* emb        = (const float*)d_in[0];
    const float* self_feats = (const float*)d_in[1];
    const int*   nidx       = (const int*)d_in[2];
    const int*   seg        = (const int*)d_in[3];
    float*       out        = (float*)d_out;

    const int B = in_sizes[1] / DIMS;   // self_feats is [B, 96]
    const int E = in_sizes[2];          // neighbor_idx length

    int* bounds = nullptr;
    if (ws_size >= (size_t)(B + 1) * sizeof(int)) {
        bounds = (int*)d_ws;
        const int bgrid = (E + 255) / 256;
        hipLaunchKernelGGL(bounds_scan_kernel, dim3(bgrid), dim3(256), 0, stream,
                           seg, bounds, B, E);
    }

    const int grid = (B + SEGS_PER_BLOCK - 1) / SEGS_PER_BLOCK;
    hipLaunchKernelGGL(seg_mean_concat_kernel, dim3(grid), dim3(THREADS), 0, stream,
                       emb, self_feats, nidx, seg, bounds, out, B, E);
}